// Round 1
// baseline (294.030 us; speedup 1.0000x reference)
//
#include <hip/hip_runtime.h>

// Batched MLP: out[t][x] = wl · tanh(W3·tanh(W2·tanh(W1·tanh(W0·x+b0)+b1)+b2)+b3) + bl
// t = 128 param sets, x = 4096 inputs of dim 16, hidden width 128.
//
// Strategy: one block per (t, 128-row x tile). MFMA f16 32x32x16 computing the
// transposed product G = W * H^T so the D fragment (col = x, rows = 4
// consecutive h per reg group) writes straight back into the [x][feature]
// activation layout needed by the next layer.  Weights are split-precision
// fp16 (hi + lo) so matmul products carry ~2^-21 relative error; activations
// are single fp16 (2^-11) which keeps the 4-layer amplified error ~0.3-0.7
// absolute vs the 1.175 threshold.

#define IND      16
#define LWD      128
#define XT       128
#define THREADS  256
#define PARAMS   51841

typedef _Float16 f16x8 __attribute__((ext_vector_type(8)));
typedef _Float16 f16x4 __attribute__((ext_vector_type(4)));
typedef float    f32x16 __attribute__((ext_vector_type(16)));

__device__ __forceinline__ f32x16 zero16() {
    f32x16 z;
#pragma unroll
    for (int i = 0; i < 16; ++i) z[i] = 0.0f;
    return z;
}

// tanh(x) = 1 - 2/(exp(2x)+1); exp overflow/underflow saturate correctly.
__device__ __forceinline__ float fast_tanh(float v) {
    float e = __expf(2.0f * v);
    return 1.0f - 2.0f / (e + 1.0f);
}

#define MFMA(A, B, C) __builtin_amdgcn_mfma_f32_32x32x16_f16((A), (B), (C), 0, 0, 0)

__global__ __launch_bounds__(THREADS, 1)
void mlp_kernel(const float* __restrict__ xin,
                const float* __restrict__ theta,
                float* __restrict__ out)
{
    // Activations [x][h], 256 B rows, XOR-swizzled: phys_byte = x*256 + (obyte ^ ((x&15)<<4))
    __shared__ __align__(16) _Float16 sH   [XT * LWD];
    // Weights [h][o], same swizzle by h.  hi + lo fp16 split.
    __shared__ __align__(16) _Float16 sWhi [LWD * LWD];
    __shared__ __align__(16) _Float16 sWlo [LWD * LWD];
    // Layer-0 operands, 32 B rows, linear (one-shot, conflicts tolerated).
    __shared__ __align__(16) _Float16 sX0hi[XT * IND];
    __shared__ __align__(16) _Float16 sX0lo[XT * IND];
    __shared__ __align__(16) _Float16 sW0hi[LWD * IND];
    __shared__ __align__(16) _Float16 sW0lo[LWD * IND];
    __shared__ float sB[2][LWD];     // bias double-buffer (stage next while using prev)
    __shared__ float sWl[LWD + 1];   // final weights + final bias

    const int tid = threadIdx.x;
    const int bid = blockIdx.x;
    // XCD-bijective remap: XCD k (= bid%8) owns sw in [k*512,(k+1)*512) -> 16 theta rows,
    // so each theta row is HBM-fetched ~once and stays L2-resident per XCD.
    const int sw  = (bid & 7) * 512 + (bid >> 3);
    const int t   = sw >> 5;
    const int xt  = sw & 31;

    const float* __restrict__ th = theta + (size_t)t * PARAMS;
    const float* __restrict__ xg = xin   + (size_t)xt * (XT * IND);

    // ---------------- stage layer-0 operands ----------------
#pragma unroll
    for (int j = 0; j < 2; ++j) {                       // x tile: 2048 floats, hi/lo
        const int flat = j * 1024 + tid * 4;
        const float4 v = *reinterpret_cast<const float4*>(xg + flat);
        _Float16 h0 = (_Float16)v.x, h1 = (_Float16)v.y, h2 = (_Float16)v.z, h3 = (_Float16)v.w;
        f16x4 ph = {h0, h1, h2, h3};
        f16x4 pl = {(_Float16)(v.x - (float)h0), (_Float16)(v.y - (float)h1),
                    (_Float16)(v.z - (float)h2), (_Float16)(v.w - (float)h3)};
        *reinterpret_cast<f16x4*>(&sX0hi[flat]) = ph;
        *reinterpret_cast<f16x4*>(&sX0lo[flat]) = pl;
    }
#pragma unroll
    for (int j = 0; j < 2; ++j) {                       // W0: 2048 floats, hi/lo
        const int flat = j * 1024 + tid * 4;
        const float a0 = th[flat], a1 = th[flat + 1], a2 = th[flat + 2], a3 = th[flat + 3];
        _Float16 h0 = (_Float16)a0, h1 = (_Float16)a1, h2 = (_Float16)a2, h3 = (_Float16)a3;
        f16x4 ph = {h0, h1, h2, h3};
        f16x4 pl = {(_Float16)(a0 - (float)h0), (_Float16)(a1 - (float)h1),
                    (_Float16)(a2 - (float)h2), (_Float16)(a3 - (float)h3)};
        *reinterpret_cast<f16x4*>(&sW0hi[flat]) = ph;
        *reinterpret_cast<f16x4*>(&sW0lo[flat]) = pl;
    }
    if (tid < LWD) sB[0][tid] = th[IND * LWD + tid];    // b0
    __syncthreads();

    const int lane  = tid & 63;
    const int w     = tid >> 6;
    const int r31   = lane & 31;
    const int khalf = lane >> 5;           // which K-half of the fragment
    const int hb    = (w >> 1) * 64;       // wave's feature-block (A rows)
    const int xb    = (w & 1) * 64;        // wave's x-block       (B cols)
    const int hA0 = hb + r31,  hA1 = hb + 32 + r31;
    const int xB0 = xb + r31,  xB1 = xb + 32 + r31;
    const int swzA0 = (hA0 & 15) << 4, swzA1 = (hA1 & 15) << 4;
    const int swzB0 = (xB0 & 15) << 4, swzB1 = (xB1 & 15) << 4;

    f32x16 acc[2][2];

    // ---------------- layer 0 (K = 16 exactly: one MFMA K-step) ----------------
    {
        const int kb = khalf * 16;   // byte offset in 32-B row
        f16x8 ah[2], al[2], bh[2], bl[2];
        ah[0] = *reinterpret_cast<const f16x8*>((const char*)sW0hi + hA0 * 32 + kb);
        ah[1] = *reinterpret_cast<const f16x8*>((const char*)sW0hi + hA1 * 32 + kb);
        al[0] = *reinterpret_cast<const f16x8*>((const char*)sW0lo + hA0 * 32 + kb);
        al[1] = *reinterpret_cast<const f16x8*>((const char*)sW0lo + hA1 * 32 + kb);
        bh[0] = *reinterpret_cast<const f16x8*>((const char*)sX0hi + xB0 * 32 + kb);
        bh[1] = *reinterpret_cast<const f16x8*>((const char*)sX0hi + xB1 * 32 + kb);
        bl[0] = *reinterpret_cast<const f16x8*>((const char*)sX0lo + xB0 * 32 + kb);
        bl[1] = *reinterpret_cast<const f16x8*>((const char*)sX0lo + xB1 * 32 + kb);
#pragma unroll
        for (int tt = 0; tt < 2; ++tt)
#pragma unroll
            for (int tx = 0; tx < 2; ++tx) {
                f32x16 a = zero16();
                a = MFMA(al[tt], bh[tx], a);   // Wlo * xhi
                a = MFMA(ah[tt], bl[tx], a);   // Whi * xlo
                a = MFMA(ah[tt], bh[tx], a);   // Whi * xhi
                acc[tt][tx] = a;
            }
    }

    // Epilogue: bias + tanh + write h into sH ([x][h], swizzled).
    // D layout (32x32): col = lane&31 (= x), row = (reg&3) + 8*(reg>>2) + 4*(lane>>5) (= h).
    auto epilogue = [&](const float* __restrict__ bb) {
#pragma unroll
        for (int tt = 0; tt < 2; ++tt)
#pragma unroll
            for (int tx = 0; tx < 2; ++tx) {
                const int xw  = xb + tx * 32 + r31;
                const int swz = (xw & 15) << 4;
#pragma unroll
                for (int g = 0; g < 4; ++g) {
                    const int hbase = hb + tt * 32 + g * 8 + khalf * 4;
                    f16x4 pk;
#pragma unroll
                    for (int q = 0; q < 4; ++q) {
                        const float v = acc[tt][tx][g * 4 + q] + bb[hbase + q];
                        pk[q] = (_Float16)fast_tanh(v);
                    }
                    *reinterpret_cast<f16x4*>((char*)sH + xw * 256 + ((hbase * 2) ^ swz)) = pk;
                }
            }
    };

    // ---------------- hidden layers 1..3 ----------------
    for (int l = 0; l < 3; ++l) {
        __syncthreads();   // all reads of sH / sW(hi,lo) from previous matmul done

        // Stage W_{l+1} hi/lo (swizzled) + b_{l+1}; global loads issue first so
        // their latency overlaps the tanh epilogue below.
        const float* __restrict__ wsrc = th + 2176 + l * 16512;
#pragma unroll
        for (int j = 0; j < 16; ++j) {
            const int flat = j * 1024 + tid * 4;
            const int hrow = flat >> 7;
            const int o    = flat & 127;
            const float a0 = wsrc[flat], a1 = wsrc[flat + 1], a2 = wsrc[flat + 2], a3 = wsrc[flat + 3];
            _Float16 h0 = (_Float16)a0, h1 = (_Float16)a1, h2 = (_Float16)a2, h3 = (_Float16)a3;
            f16x4 ph = {h0, h1, h2, h3};
            f16x4 pl = {(_Float16)(a0 - (float)h0), (_Float16)(a1 - (float)h1),
                        (_Float16)(a2 - (float)h2), (_Float16)(a3 - (float)h3)};
            const int boff = hrow * 256 + ((o * 2) ^ ((hrow & 15) << 4));
            *reinterpret_cast<f16x4*>((char*)sWhi + boff) = ph;
            *reinterpret_cast<f16x4*>((char*)sWlo + boff) = pl;
        }
        if (tid < LWD) sB[(l + 1) & 1][tid] = wsrc[LWD * LWD + tid];
        if (l == 2) {
            if (tid < LWD) sWl[tid] = th[51712 + tid];
            if (tid == LWD) sWl[LWD] = th[51840];
        }

        epilogue(sB[l & 1]);          // h_{l+1} -> sH
        __syncthreads();              // sH + sW + sB visible

        // acc = W_{l+1}(hi+lo) * h  (G = W * H^T; A rows = features, B cols = x)
#pragma unroll
        for (int tt = 0; tt < 2; ++tt)
#pragma unroll
            for (int tx = 0; tx < 2; ++tx) acc[tt][tx] = zero16();
#pragma unroll
        for (int kc = 0; kc < 8; ++kc) {
            const int kb = kc * 32 + khalf * 16;
            f16x8 ah[2], al[2], bv[2];
            ah[0] = *reinterpret_cast<const f16x8*>((const char*)sWhi + hA0 * 256 + (kb ^ swzA0));
            ah[1] = *reinterpret_cast<const f16x8*>((const char*)sWhi + hA1 * 256 + (kb ^ swzA1));
            al[0] = *reinterpret_cast<const f16x8*>((const char*)sWlo + hA0 * 256 + (kb ^ swzA0));
            al[1] = *reinterpret_cast<const f16x8*>((const char*)sWlo + hA1 * 256 + (kb ^ swzA1));
            bv[0] = *reinterpret_cast<const f16x8*>((const char*)sH   + xB0 * 256 + (kb ^ swzB0));
            bv[1] = *reinterpret_cast<const f16x8*>((const char*)sH   + xB1 * 256 + (kb ^ swzB1));
#pragma unroll
            for (int tt = 0; tt < 2; ++tt)
#pragma unroll
                for (int tx = 0; tx < 2; ++tx) {
                    acc[tt][tx] = MFMA(al[tt], bv[tx], acc[tt][tx]);
                    acc[tt][tx] = MFMA(ah[tt], bv[tx], acc[tt][tx]);
                }
        }
    }

    __syncthreads();        // last matmul's sH reads done
    epilogue(sB[1]);        // h4 -> sH (b3 lives in slot 1)
    __syncthreads();

    // ---------------- final layer: out[x] = wl . h4[x] + bl ----------------
    if (tid < XT) {
        const int r   = tid;
        const int swz = (r & 15) << 4;
        float s = 0.0f;
#pragma unroll
        for (int c = 0; c < 16; ++c) {
            const int hc = (c + r) & 15;    // rotate start chunk to spread LDS banks
            const f16x8 hv = *reinterpret_cast<const f16x8*>(
                (const char*)sH + r * 256 + ((hc * 16) ^ swz));
#pragma unroll
            for (int q = 0; q < 8; ++q) s += (float)hv[q] * sWl[hc * 8 + q];
        }
        out[(size_t)t * 4096 + (size_t)xt * XT + r] = s + sWl[LWD];
    }
}

extern "C" void kernel_launch(void* const* d_in, const int* in_sizes, int n_in,
                              void* d_out, int out_size, void* d_ws, size_t ws_size,
                              hipStream_t stream)
{
    const float* x     = (const float*)d_in[0];
    const float* theta = (const float*)d_in[1];
    float* out = (float*)d_out;
    // 128 theta * 32 x-tiles = 4096 blocks
    mlp_kernel<<<dim3(128 * (4096 / XT)), dim3(THREADS), 0, stream>>>(x, theta, out);
}

// Round 2
// 180.800 us; speedup vs baseline: 1.6263x; 1.6263x over previous
//
#include <hip/hip_runtime.h>

// Batched MLP, round 2.
// - prep_kernel: one-time (per launch) conversion of theta -> fp16 images in d_ws:
//     * hidden W1..W3: single-fp16, PRE-SWIZZLED 32KB byte images (LDS-ready)
//     * W0 and x: hi/lo fp16 split (layer 0 keeps split precision; K=16 so cheap)
// - mlp_main: stages weight images with global_load_lds (width 16, linear dest),
//   66 KB LDS -> 2 blocks/CU, single-fp16 MFMA for hidden layers.
// - Fallback to the round-1 kernel if ws_size is too small.

#define IND      16
#define LWD      128
#define XT       128
#define THREADS  256
#define PARAMS   51841

#define WS_L0    12582912                  // 128*3*32768 hidden-W images
#define WS_X     (WS_L0 + 128 * 8192)      // + per-t layer0 W images (hi|lo)
#define WS_TOTAL (WS_X + 32 * 8192)        // + per-xtile x images (hi|lo) = 13,893,632

typedef _Float16 f16x8 __attribute__((ext_vector_type(8)));
typedef _Float16 f16x4 __attribute__((ext_vector_type(4)));
typedef float    f32x16 __attribute__((ext_vector_type(16)));

__device__ __forceinline__ f32x16 zero16() {
    f32x16 z;
#pragma unroll
    for (int i = 0; i < 16; ++i) z[i] = 0.0f;
    return z;
}

__device__ __forceinline__ float fast_tanh(float v) {
    float e = __expf(2.0f * v);
    return 1.0f - 2.0f / (e + 1.0f);
}

#define MFMA(A, B, C) __builtin_amdgcn_mfma_f32_32x32x16_f16((A), (B), (C), 0, 0, 0)

__device__ __forceinline__ void gload16(const void* g, void* l) {
    __builtin_amdgcn_global_load_lds(
        (const __attribute__((address_space(1))) void*)g,
        (__attribute__((address_space(3))) void*)l, 16, 0, 0);
}

// Convert 8 consecutive floats to hi/lo fp16 pairs at hidst / lodst.
__device__ __forceinline__ void conv8(const float* __restrict__ s, char* hidst, char* lodst) {
    float v[8];
    *reinterpret_cast<float4*>(v)     = *reinterpret_cast<const float4*>(s);
    *reinterpret_cast<float4*>(v + 4) = *reinterpret_cast<const float4*>(s + 4);
    f16x8 hi, lo;
#pragma unroll
    for (int i = 0; i < 8; ++i) {
        hi[i] = (_Float16)v[i];
        lo[i] = (_Float16)(v[i] - (float)hi[i]);
    }
    *reinterpret_cast<f16x8*>(hidst) = hi;
    *reinterpret_cast<f16x8*>(lodst) = lo;
}

// ---------------------------------------------------------------------------
// Preprocessing: build fp16 weight/input images in ws.
//  blocks [0,3072):   hidden W images, swizzled:  img[h*256 + ((o*2)^((h&15)<<4))]
//  blocks [3072,3136): W0 hi/lo rows:  ws+WS_L0+t*8192 + h*32 (lo at +4096)
//  blocks [3136,3152): x  hi/lo rows:  ws+WS_X +xt*8192 + r*32 (lo at +4096)
// ---------------------------------------------------------------------------
__global__ __launch_bounds__(256)
void prep_kernel(const float* __restrict__ theta, const float* __restrict__ xin,
                 char* __restrict__ ws)
{
    const int b = blockIdx.x, tid = threadIdx.x;
    if (b < 3072) {
        const int gid = b * 256 + tid;          // *8 elems
        const int t   = gid / 6144;
        const int r   = gid % 6144;
        const int l   = r / 2048;
        const int e   = (r % 2048) * 8;
        const int h   = e >> 7, o = e & 127;
        const float* src = theta + (size_t)t * PARAMS + 2176 + l * 16512 + h * 128 + o;
        float v[8];
        *reinterpret_cast<float4*>(v)     = *reinterpret_cast<const float4*>(src);
        *reinterpret_cast<float4*>(v + 4) = *reinterpret_cast<const float4*>(src + 4);
        f16x8 p;
#pragma unroll
        for (int i = 0; i < 8; ++i) p[i] = (_Float16)v[i];
        char* img = ws + ((size_t)(t * 3 + l) << 15);
        *reinterpret_cast<f16x8*>(img + h * 256 + ((o * 2) ^ ((h & 15) << 4))) = p;
    } else if (b < 3136) {
        const int gid = (b - 3072) * 256 + tid;  // 16384 rows: t*128 + h
        const int t = gid >> 7, h = gid & 127;
        const float* src = theta + (size_t)t * PARAMS + h * IND;
        char* dst = ws + WS_L0 + (size_t)t * 8192 + h * 32;
        conv8(src,     dst,      dst + 4096);
        conv8(src + 8, dst + 16, dst + 4096 + 16);
    } else {
        const int row = (b - 3136) * 256 + tid;  // 4096 x-rows
        const float* src = xin + (size_t)row * IND;
        char* dst = ws + WS_X + (size_t)(row >> 7) * 8192 + (row & 127) * 32;
        conv8(src,     dst,      dst + 4096);
        conv8(src + 8, dst + 16, dst + 4096 + 16);
    }
}

// ---------------------------------------------------------------------------
// Main kernel. LDS 66 KB -> 2 blocks/CU.
// ---------------------------------------------------------------------------
__global__ __launch_bounds__(THREADS, 2)
void mlp_main(const float* __restrict__ theta, const char* __restrict__ ws,
              float* __restrict__ out)
{
    __shared__ __align__(16) _Float16 sH[XT * LWD];     // 32 KB; bytes [0,16K) double as layer0 operands
    __shared__ __align__(16) _Float16 sW[LWD * LWD];    // 32 KB swizzled weight image
    __shared__ float sB[2][LWD];
    __shared__ float sWl[LWD + 1];

    const int tid = threadIdx.x;
    const int bid = blockIdx.x;
    const int sw  = (bid & 7) * 512 + (bid >> 3);   // XCD-bijective (4096 % 8 == 0)
    const int t   = sw >> 5;
    const int xt  = sw & 31;
    const float* __restrict__ th = theta + (size_t)t * PARAMS;

    const int lane = tid & 63, w = tid >> 6;

    // stage layer0 operands: x image -> sH[0,8K), W0 image -> sH[8K,16K)
    {
        const char* gx = ws + WS_X  + (size_t)xt * 8192;
        const char* gw = ws + WS_L0 + (size_t)t  * 8192;
        char* lb = (char*)sH;
#pragma unroll
        for (int c = w; c < 8; c += 4) {
            gload16(gx + c * 1024 + lane * 16, lb + c * 1024);
            gload16(gw + c * 1024 + lane * 16, lb + 8192 + c * 1024);
        }
    }
    if (tid < LWD) sB[0][tid] = th[IND * LWD + tid];    // b0
    __syncthreads();

    const int r31   = lane & 31;
    const int khalf = lane >> 5;
    const int hb    = (w >> 1) * 64;
    const int xb    = (w & 1) * 64;
    const int hA0 = hb + r31,  hA1 = hb + 32 + r31;
    const int xB0 = xb + r31,  xB1 = xb + 32 + r31;
    const int swzA0 = (hA0 & 15) << 4, swzA1 = (hA1 & 15) << 4;
    const int swzB0 = (xB0 & 15) << 4, swzB1 = (xB1 & 15) << 4;

    f32x16 acc[2][2];

    // ---------------- layer 0: hi/lo x hi/lo, K = 16 ----------------
    {
        const int kb = khalf * 16;
        const char* base = (const char*)sH;
        f16x8 BH[2], BL[2], AH[2], AL[2];
        BH[0] = *reinterpret_cast<const f16x8*>(base + xB0 * 32 + kb);
        BH[1] = *reinterpret_cast<const f16x8*>(base + xB1 * 32 + kb);
        BL[0] = *reinterpret_cast<const f16x8*>(base + 4096 + xB0 * 32 + kb);
        BL[1] = *reinterpret_cast<const f16x8*>(base + 4096 + xB1 * 32 + kb);
        AH[0] = *reinterpret_cast<const f16x8*>(base + 8192 + hA0 * 32 + kb);
        AH[1] = *reinterpret_cast<const f16x8*>(base + 8192 + hA1 * 32 + kb);
        AL[0] = *reinterpret_cast<const f16x8*>(base + 12288 + hA0 * 32 + kb);
        AL[1] = *reinterpret_cast<const f16x8*>(base + 12288 + hA1 * 32 + kb);
#pragma unroll
        for (int tt = 0; tt < 2; ++tt)
#pragma unroll
            for (int tx = 0; tx < 2; ++tx) {
                f32x16 a = zero16();
                a = MFMA(AL[tt], BH[tx], a);
                a = MFMA(AH[tt], BL[tx], a);
                a = MFMA(AH[tt], BH[tx], a);
                acc[tt][tx] = a;
            }
    }

    // bias + tanh + write h into sH ([x][h], 256 B rows, swizzled)
    auto epilogue = [&](const float* __restrict__ bb) {
#pragma unroll
        for (int tt = 0; tt < 2; ++tt)
#pragma unroll
            for (int tx = 0; tx < 2; ++tx) {
                const int xw  = xb + tx * 32 + r31;
                const int swz = (xw & 15) << 4;
#pragma unroll
                for (int g = 0; g < 4; ++g) {
                    const int hbase = hb + tt * 32 + g * 8 + khalf * 4;
                    f16x4 pk;
#pragma unroll
                    for (int q = 0; q < 4; ++q) {
                        const float v = acc[tt][tx][g * 4 + q] + bb[hbase + q];
                        pk[q] = (_Float16)fast_tanh(v);
                    }
                    *reinterpret_cast<f16x4*>((char*)sH + xw * 256 + ((hbase * 2) ^ swz)) = pk;
                }
            }
    };

    // ---------------- hidden layers 1..3 (single fp16 weights) ----------------
    for (int l = 0; l < 3; ++l) {
        __syncthreads();   // prior MFMA reads of sH/sW done

        const char* gsrc = ws + ((size_t)(t * 3 + l) << 15);
        char* lw = (char*)sW;
#pragma unroll
        for (int c = w; c < 32; c += 4)
            gload16(gsrc + c * 1024 + lane * 16, lw + c * 1024);

        if (tid < LWD) sB[(l + 1) & 1][tid] = th[2176 + l * 16512 + 16384 + tid];
        if (l == 2) {
            if (tid < LWD) sWl[tid] = th[51712 + tid];
            if (tid == 128) sWl[LWD] = th[51840];
        }

        epilogue(sB[l & 1]);          // overlaps with weight loads in flight
        __syncthreads();              // drains vmcnt: sW + sH + sB visible

#pragma unroll
        for (int tt = 0; tt < 2; ++tt)
#pragma unroll
            for (int tx = 0; tx < 2; ++tx) acc[tt][tx] = zero16();
#pragma unroll
        for (int kc = 0; kc < 8; ++kc) {
            const int kb = kc * 32 + khalf * 16;
            f16x8 a0, a1, b0, b1;
            a0 = *reinterpret_cast<const f16x8*>((const char*)sW + hA0 * 256 + (kb ^ swzA0));
            a1 = *reinterpret_cast<const f16x8*>((const char*)sW + hA1 * 256 + (kb ^ swzA1));
            b0 = *reinterpret_cast<const f16x8*>((const char*)sH + xB0 * 256 + (kb ^ swzB0));
            b1 = *reinterpret_cast<const f16x8*>((const char*)sH + xB1 * 256 + (kb ^ swzB1));
            acc[0][0] = MFMA(a0, b0, acc[0][0]);
            acc[0][1] = MFMA(a0, b1, acc[0][1]);
            acc[1][0] = MFMA(a1, b0, acc[1][0]);
            acc[1][1] = MFMA(a1, b1, acc[1][1]);
        }
    }

    __syncthreads();
    epilogue(sB[1]);        // b3
    __syncthreads();

    // ---------------- final layer ----------------
    if (tid < XT) {
        const int r   = tid;
        const int swz = (r & 15) << 4;
        float s = 0.0f;
#pragma unroll
        for (int c = 0; c < 16; ++c) {
            const int hc = (c + r) & 15;
            const f16x8 hv = *reinterpret_cast<const f16x8*>(
                (const char*)sH + r * 256 + ((hc * 16) ^ swz));
#pragma unroll
            for (int q = 0; q < 8; ++q) s += (float)hv[q] * sWl[hc * 8 + q];
        }
        out[(size_t)t * 4096 + (size_t)xt * XT + r] = s + sWl[LWD];
    }
}

// ---------------------------------------------------------------------------
// Fallback: round-1 kernel (self-contained, no workspace). Known-good.
// ---------------------------------------------------------------------------
__global__ __launch_bounds__(THREADS, 1)
void mlp_kernel_fb(const float* __restrict__ xin,
                   const float* __restrict__ theta,
                   float* __restrict__ out)
{
    __shared__ __align__(16) _Float16 sH   [XT * LWD];
    __shared__ __align__(16) _Float16 sWhi [LWD * LWD];
    __shared__ __align__(16) _Float16 sWlo [LWD * LWD];
    __shared__ __align__(16) _Float16 sX0hi[XT * IND];
    __shared__ __align__(16) _Float16 sX0lo[XT * IND];
    __shared__ __align__(16) _Float16 sW0hi[LWD * IND];
    __shared__ __align__(16) _Float16 sW0lo[LWD * IND];
    __shared__ float sB[2][LWD];
    __shared__ float sWl[LWD + 1];

    const int tid = threadIdx.x;
    const int bid = blockIdx.x;
    const int sw  = (bid & 7) * 512 + (bid >> 3);
    const int t   = sw >> 5;
    const int xt  = sw & 31;

    const float* __restrict__ th = theta + (size_t)t * PARAMS;
    const float* __restrict__ xg = xin   + (size_t)xt * (XT * IND);

#pragma unroll
    for (int j = 0; j < 2; ++j) {
        const int flat = j * 1024 + tid * 4;
        const float4 v = *reinterpret_cast<const float4*>(xg + flat);
        _Float16 h0 = (_Float16)v.x, h1 = (_Float16)v.y, h2 = (_Float16)v.z, h3 = (_Float16)v.w;
        f16x4 ph = {h0, h1, h2, h3};
        f16x4 pl = {(_Float16)(v.x - (float)h0), (_Float16)(v.y - (float)h1),
                    (_Float16)(v.z - (float)h2), (_Float16)(v.w - (float)h3)};
        *reinterpret_cast<f16x4*>(&sX0hi[flat]) = ph;
        *reinterpret_cast<f16x4*>(&sX0lo[flat]) = pl;
    }
#pragma unroll
    for (int j = 0; j < 2; ++j) {
        const int flat = j * 1024 + tid * 4;
        const float a0 = th[flat], a1 = th[flat + 1], a2 = th[flat + 2], a3 = th[flat + 3];
        _Float16 h0 = (_Float16)a0, h1 = (_Float16)a1, h2 = (_Float16)a2, h3 = (_Float16)a3;
        f16x4 ph = {h0, h1, h2, h3};
        f16x4 pl = {(_Float16)(a0 - (float)h0), (_Float16)(a1 - (float)h1),
                    (_Float16)(a2 - (float)h2), (_Float16)(a3 - (float)h3)};
        *reinterpret_cast<f16x4*>(&sW0hi[flat]) = ph;
        *reinterpret_cast<f16x4*>(&sW0lo[flat]) = pl;
    }
    if (tid < LWD) sB[0][tid] = th[IND * LWD + tid];
    __syncthreads();

    const int lane  = tid & 63;
    const int w     = tid >> 6;
    const int r31   = lane & 31;
    const int khalf = lane >> 5;
    const int hb    = (w >> 1) * 64;
    const int xb    = (w & 1) * 64;
    const int hA0 = hb + r31,  hA1 = hb + 32 + r31;
    const int xB0 = xb + r31,  xB1 = xb + 32 + r31;
    const int swzA0 = (hA0 & 15) << 4, swzA1 = (hA1 & 15) << 4;
    const int swzB0 = (xB0 & 15) << 4, swzB1 = (xB1 & 15) << 4;

    f32x16 acc[2][2];

    {
        const int kb = khalf * 16;
        f16x8 ah[2], al[2], bh[2], bl[2];
        ah[0] = *reinterpret_cast<const f16x8*>((const char*)sW0hi + hA0 * 32 + kb);
        ah[1] = *reinterpret_cast<const f16x8*>((const char*)sW0hi + hA1 * 32 + kb);
        al[0] = *reinterpret_cast<const f16x8*>((const char*)sW0lo + hA0 * 32 + kb);
        al[1] = *reinterpret_cast<const f16x8*>((const char*)sW0lo + hA1 * 32 + kb);
        bh[0] = *reinterpret_cast<const f16x8*>((const char*)sX0hi + xB0 * 32 + kb);
        bh[1] = *reinterpret_cast<const f16x8*>((const char*)sX0hi + xB1 * 32 + kb);
        bl[0] = *reinterpret_cast<const f16x8*>((const char*)sX0lo + xB0 * 32 + kb);
        bl[1] = *reinterpret_cast<const f16x8*>((const char*)sX0lo + xB1 * 32 + kb);
#pragma unroll
        for (int tt = 0; tt < 2; ++tt)
#pragma unroll
            for (int tx = 0; tx < 2; ++tx) {
                f32x16 a = zero16();
                a = MFMA(al[tt], bh[tx], a);
                a = MFMA(ah[tt], bl[tx], a);
                a = MFMA(ah[tt], bh[tx], a);
                acc[tt][tx] = a;
            }
    }

    auto epilogue = [&](const float* __restrict__ bb) {
#pragma unroll
        for (int tt = 0; tt < 2; ++tt)
#pragma unroll
            for (int tx = 0; tx < 2; ++tx) {
                const int xw  = xb + tx * 32 + r31;
                const int swz = (xw & 15) << 4;
#pragma unroll
                for (int g = 0; g < 4; ++g) {
                    const int hbase = hb + tt * 32 + g * 8 + khalf * 4;
                    f16x4 pk;
#pragma unroll
                    for (int q = 0; q < 4; ++q) {
                        const float v = acc[tt][tx][g * 4 + q] + bb[hbase + q];
                        pk[q] = (_Float16)fast_tanh(v);
                    }
                    *reinterpret_cast<f16x4*>((char*)sH + xw * 256 + ((hbase * 2) ^ swz)) = pk;
                }
            }
    };

    for (int l = 0; l < 3; ++l) {
        __syncthreads();
        const float* __restrict__ wsrc = th + 2176 + l * 16512;
#pragma unroll
        for (int j = 0; j < 16; ++j) {
            const int flat = j * 1024 + tid * 4;
            const int hrow = flat >> 7;
            const int o    = flat & 127;
            const float a0 = wsrc[flat], a1 = wsrc[flat + 1], a2 = wsrc[flat + 2], a3 = wsrc[flat + 3];
            _Float16 h0 = (_Float16)a0, h1 = (_Float16)a1, h2 = (_Float16)a2, h3 = (_Float16)a3;
            f16x4 ph = {h0, h1, h2, h3};
            f16x4 pl = {(_Float16)(a0 - (float)h0), (_Float16)(a1 - (float)h1),
                        (_Float16)(a2 - (float)h2), (_Float16)(a3 - (float)h3)};
            const int boff = hrow * 256 + ((o * 2) ^ ((hrow & 15) << 4));
            *reinterpret_cast<f16x4*>((char*)sWhi + boff) = ph;
            *reinterpret_cast<f16x4*>((char*)sWlo + boff) = pl;
        }
        if (tid < LWD) sB[(l + 1) & 1][tid] = wsrc[LWD * LWD + tid];
        if (l == 2) {
            if (tid < LWD) sWl[tid] = th[51712 + tid];
            if (tid == LWD) sWl[LWD] = th[51840];
        }

        epilogue(sB[l & 1]);
        __syncthreads();

#pragma unroll
        for (int tt = 0; tt < 2; ++tt)
#pragma unroll
            for (int tx = 0; tx < 2; ++tx) acc[tt][tx] = zero16();
#pragma unroll
        for (int kc = 0; kc < 8; ++kc) {
            const int kb = kc * 32 + khalf * 16;
            f16x8 ah[2], al[2], bv[2];
            ah[0] = *reinterpret_cast<const f16x8*>((const char*)sWhi + hA0 * 256 + (kb ^ swzA0));
            ah[1] = *reinterpret_cast<const f16x8*>((const char*)sWhi + hA1 * 256 + (kb ^ swzA1));
            al[0] = *reinterpret_cast<const f16x8*>((const char*)sWlo + hA0 * 256 + (kb ^ swzA0));
            al[1] = *reinterpret_cast<const f16x8*>((const char*)sWlo + hA1 * 256 + (kb ^ swzA1));
            bv[0] = *reinterpret_cast<const f16x8*>((const char*)sH   + xB0 * 256 + (kb ^ swzB0));
            bv[1] = *reinterpret_cast<const f16x8*>((const char*)sH   + xB1 * 256 + (kb ^ swzB1));
#pragma unroll
            for (int tt = 0; tt < 2; ++tt)
#pragma unroll
                for (int tx = 0; tx < 2; ++tx) {
                    acc[tt][tx] = MFMA(al[tt], bv[tx], acc[tt][tx]);
                    acc[tt][tx] = MFMA(ah[tt], bv[tx], acc[tt][tx]);
                }
        }
    }

    __syncthreads();
    epilogue(sB[1]);
    __syncthreads();

    if (tid < XT) {
        const int r   = tid;
        const int swz = (r & 15) << 4;
        float s = 0.0f;
#pragma unroll
        for (int c = 0; c < 16; ++c) {
            const int hc = (c + r) & 15;
            const f16x8 hv = *reinterpret_cast<const f16x8*>(
                (const char*)sH + r * 256 + ((hc * 16) ^ swz));
#pragma unroll
            for (int q = 0; q < 8; ++q) s += (float)hv[q] * sWl[hc * 8 + q];
        }
        out[(size_t)t * 4096 + (size_t)xt * XT + r] = s + sWl[LWD];
    }
}

extern "C" void kernel_launch(void* const* d_in, const int* in_sizes, int n_in,
                              void* d_out, int out_size, void* d_ws, size_t ws_size,
                              hipStream_t stream)
{
    const float* x     = (const float*)d_in[0];
    const float* theta = (const float*)d_in[1];
    float* out = (float*)d_out;

    if (ws_size >= (size_t)WS_TOTAL) {
        prep_kernel<<<dim3(3152), dim3(256), 0, stream>>>(theta, x, (char*)d_ws);
        mlp_main<<<dim3(4096), dim3(THREADS), 0, stream>>>(theta, (const char*)d_ws, out);
    } else {
        mlp_kernel_fb<<<dim3(4096), dim3(THREADS), 0, stream>>>(x, theta, out);
    }
}

// Round 3
// 105.294 us; speedup vs baseline: 2.7925x; 1.7171x over previous
//
#include <hip/hip_runtime.h>

// Batched MLP, round 3: in-register activation handoff.
// One wave owns 128h x 32x. MFMA D-frag (col=x, row=h) is re-packed into the
// next layer's B-frag via f16 pack + ds_bpermute(lane^32) half-exchange --
// activations never touch LDS. LDS holds only the current W (32KB, staged
// fragment-linear via global_load_lds; A-reads are canonical base+lane*16 +
// immediate: conflict-free, no address VALU). Bias folds into acc init.
// 2 barriers/layer; W_{l+1} stage hides under the tanh/pack phase.

#define IND      16
#define LWD      128
#define THREADS  256
#define PARAMS   51841

#define WS_L0    12582912                  // 128*3*32768 hidden-W frag images
#define WS_X     (WS_L0 + 128 * 8192)      // + per-t layer0 W images (hi|lo)
#define WS_TOTAL (WS_X + 32 * 8192)        // + per-xtile x images (hi|lo)

#define LDS_W    0
#define LDS_B    32768                      // b1..b3: 3*512 B
#define LDS_WL   (32768 + 1536)             // wl (512B) + bl (4B)
#define LDS_SZ   (32768 + 1536 + 520)

typedef _Float16 f16x8 __attribute__((ext_vector_type(8)));
typedef _Float16 f16x4 __attribute__((ext_vector_type(4)));
typedef float    f32x16 __attribute__((ext_vector_type(16)));
typedef float    f32x4v __attribute__((ext_vector_type(4)));

union U4 { unsigned u[4]; f16x8 v; };

// tanh(x) = 1 - 2/(1+2^(2*log2e*x)); saturates correctly at +/-inf, no NaN.
__device__ __forceinline__ float fast_tanh(float v) {
    float e = __builtin_amdgcn_exp2f(v * 2.8853900817779268f);
    return 1.0f - 2.0f * __builtin_amdgcn_rcpf(e + 1.0f);
}
__device__ __forceinline__ unsigned pkf16(float a, float b) {
    unsigned short ua = __builtin_bit_cast(unsigned short, (_Float16)a);
    unsigned short ub = __builtin_bit_cast(unsigned short, (_Float16)b);
    return (unsigned)ua | ((unsigned)ub << 16);
}
#define MFMA(A, B, C) __builtin_amdgcn_mfma_f32_32x32x16_f16((A), (B), (C), 0, 0, 0)

__device__ __forceinline__ void gload16(const void* g, void* l) {
    __builtin_amdgcn_global_load_lds(
        (const __attribute__((address_space(1))) void*)g,
        (__attribute__((address_space(3))) void*)l, 16, 0, 0);
}

__device__ __forceinline__ void conv8(const float* __restrict__ s, char* hidst, char* lodst) {
    float v[8];
    *reinterpret_cast<float4*>(v)     = *reinterpret_cast<const float4*>(s);
    *reinterpret_cast<float4*>(v + 4) = *reinterpret_cast<const float4*>(s + 4);
    f16x8 hi, lo;
#pragma unroll
    for (int i = 0; i < 8; ++i) {
        hi[i] = (_Float16)v[i];
        lo[i] = (_Float16)(v[i] - (float)hi[i]);
    }
    *reinterpret_cast<f16x8*>(hidst) = hi;
    *reinterpret_cast<f16x8*>(lodst) = lo;
}

// ---------------------------------------------------------------------------
// prep: build images in ws.
//  blocks [0,3072):    hidden W fragment-linear f16 images:
//     img(t,li) + ((h>>5)*8 + kc)*1024 + ((k8)*32 + (h&31))*16
//       holds W[h][kc*16 + k8*8 + 0..7]   (A-frag order: 1KB per (tile,kc))
//  blocks [3072,3136):  W0 hi/lo rows: ws+WS_L0+t*8192 + h*32 (lo at +4096)
//  blocks [3136,3152):  x  hi/lo rows: ws+WS_X +xt*8192 + r*32 (lo at +4096)
// ---------------------------------------------------------------------------
__global__ __launch_bounds__(256)
void prep_kernel(const float* __restrict__ theta, const float* __restrict__ xin,
                 char* __restrict__ ws)
{
    const int b = blockIdx.x, tid = threadIdx.x;
    if (b < 3072) {
        const int t = b / 24, rem = b % 24, li = rem >> 3, hblk = rem & 7;
        const int h  = hblk * 16 + (tid >> 4);
        const int kc = (tid >> 1) & 7, kh = tid & 1;
        const float* src = theta + (size_t)t * PARAMS + 2176 + li * 16512
                         + h * 128 + kc * 16 + kh * 8;
        float v[8];
        *reinterpret_cast<float4*>(v)     = *reinterpret_cast<const float4*>(src);
        *reinterpret_cast<float4*>(v + 4) = *reinterpret_cast<const float4*>(src + 4);
        f16x8 p;
#pragma unroll
        for (int i = 0; i < 8; ++i) p[i] = (_Float16)v[i];
        char* img = ws + ((size_t)(t * 3 + li) << 15);
        *reinterpret_cast<f16x8*>(img + ((h >> 5) * 8 + kc) * 1024
                                      + (kh * 32 + (h & 31)) * 16) = p;
    } else if (b < 3136) {
        const int gid = (b - 3072) * 256 + tid;
        const int t = gid >> 7, h = gid & 127;
        const float* src = theta + (size_t)t * PARAMS + h * IND;
        char* dst = ws + WS_L0 + (size_t)t * 8192 + h * 32;
        conv8(src,     dst,      dst + 4096);
        conv8(src + 8, dst + 16, dst + 4096 + 16);
    } else {
        const int row = (b - 3136) * 256 + tid;
        const float* src = xin + (size_t)row * IND;
        char* dst = ws + WS_X + (size_t)(row >> 7) * 8192 + (row & 127) * 32;
        conv8(src,     dst,      dst + 4096);
        conv8(src + 8, dst + 16, dst + 4096 + 16);
    }
}

// ---------------------------------------------------------------------------
// main
// ---------------------------------------------------------------------------
__global__ __launch_bounds__(THREADS, 3)
void mlp_main(const float* __restrict__ theta, const char* __restrict__ ws,
              float* __restrict__ out)
{
    __shared__ __align__(16) char sL[LDS_SZ];

    const int tid = threadIdx.x, bid = blockIdx.x;
    const int sw  = (bid & 7) * 512 + (bid >> 3);   // XCD-bijective (4096%8==0)
    const int t   = sw >> 5, xt = sw & 31;
    const float* __restrict__ th = theta + (size_t)t * PARAMS;
    const int lane = tid & 63, w = tid >> 6, r31 = lane & 31, khalf = lane >> 5;
    const int bpa  = (lane ^ 32) << 2;              // ds_bpermute byte index

    // ---- stage W1 (async, fragment-linear -> linear LDS) ----
    {
        const char* img = ws + ((size_t)(t * 3) << 15);
#pragma unroll
        for (int c = 0; c < 8; ++c)
            gload16(img + (w + c * 4) * 1024 + lane * 16, sL + (w + c * 4) * 1024);
    }
    // ---- stage biases b1..b3 + wl + bl ----
    for (int k = tid; k < 513; k += THREADS) {
        float v = (k < 384) ? th[2176 + (k >> 7) * 16512 + 16384 + (k & 127)]
                            : th[51712 + (k - 384)];
        *reinterpret_cast<float*>(sL + LDS_B + k * 4) = v;
    }

    // ---- layer 0: acc = b0; acc += W0(hi/lo) * x(hi/lo), K=16 ----
    f32x16 acc[4];
    {
        const char* w0i = ws + WS_L0 + (size_t)t  * 8192;
        const char* xi  = ws + WS_X  + (size_t)xt * 8192;
        const int ro = r31 * 32 + khalf * 16;
        const f16x8 B0h = *reinterpret_cast<const f16x8*>(xi + w * 1024 + ro);
        const f16x8 B0l = *reinterpret_cast<const f16x8*>(xi + 4096 + w * 1024 + ro);
#pragma unroll
        for (int tt = 0; tt < 4; ++tt) {
#pragma unroll
            for (int g = 0; g < 4; ++g) {
                const float4 bv = *reinterpret_cast<const float4*>(
                    th + 2048 + tt * 32 + g * 8 + khalf * 4);
                acc[tt][4 * g + 0] = bv.x; acc[tt][4 * g + 1] = bv.y;
                acc[tt][4 * g + 2] = bv.z; acc[tt][4 * g + 3] = bv.w;
            }
            const f16x8 Ah = *reinterpret_cast<const f16x8*>(w0i + tt * 1024 + ro);
            const f16x8 Al = *reinterpret_cast<const f16x8*>(w0i + 4096 + tt * 1024 + ro);
            acc[tt] = MFMA(Al, B0h, acc[tt]);
            acc[tt] = MFMA(Ah, B0l, acc[tt]);
            acc[tt] = MFMA(Ah, B0h, acc[tt]);
        }
    }

    f16x8 Bf[8];
    // tanh(acc) -> f16 pack -> assemble next-layer B-frags via lane^32 exchange.
    // Lane (khalf) holds h = tt*32 + g*8 + khalf*4 + q. Run m = tt*4+g covers
    // [8m+4*khalf, +4). Frag(kc) needs run 2kc+khalf complete: own half +
    // partner half via ds_bpermute.
    auto activate_pack = [&]() {
        unsigned P0[16], P1[16];
#pragma unroll
        for (int tt = 0; tt < 4; ++tt)
#pragma unroll
            for (int g = 0; g < 4; ++g) {
                const float v0 = fast_tanh(acc[tt][4 * g + 0]);
                const float v1 = fast_tanh(acc[tt][4 * g + 1]);
                const float v2 = fast_tanh(acc[tt][4 * g + 2]);
                const float v3 = fast_tanh(acc[tt][4 * g + 3]);
                P0[tt * 4 + g] = pkf16(v0, v1);
                P1[tt * 4 + g] = pkf16(v2, v3);
            }
#pragma unroll
        for (int kc = 0; kc < 8; ++kc) {
            const unsigned s0 = khalf ? P0[2 * kc] : P0[2 * kc + 1];
            const unsigned s1 = khalf ? P1[2 * kc] : P1[2 * kc + 1];
            const unsigned r0 = (unsigned)__builtin_amdgcn_ds_bpermute(bpa, (int)s0);
            const unsigned r1 = (unsigned)__builtin_amdgcn_ds_bpermute(bpa, (int)s1);
            U4 u;
            u.u[0] = khalf ? r0 : P0[2 * kc];
            u.u[1] = khalf ? r1 : P1[2 * kc];
            u.u[2] = khalf ? P0[2 * kc + 1] : r0;
            u.u[3] = khalf ? P1[2 * kc + 1] : r1;
            Bf[kc] = u.v;
        }
    };
    activate_pack();
    __syncthreads();            // W1 staged + biases visible

    // ---- hidden layers 1..3 ----
#pragma unroll
    for (int l = 1; l <= 3; ++l) {
        // acc = bias_l (ds_read_b128 broadcast, conflict-free)
#pragma unroll
        for (int tt = 0; tt < 4; ++tt)
#pragma unroll
            for (int g = 0; g < 4; ++g) {
                const f32x4v bv = *reinterpret_cast<const f32x4v*>(
                    sL + LDS_B + (l - 1) * 512 + (tt * 32 + g * 8) * 4 + khalf * 16);
                acc[tt][4 * g + 0] = bv[0]; acc[tt][4 * g + 1] = bv[1];
                acc[tt][4 * g + 2] = bv[2]; acc[tt][4 * g + 3] = bv[3];
            }
        // A-reads: one addr reg (lane*16) + immediate offsets; conflict-free.
#pragma unroll
        for (int kc = 0; kc < 8; ++kc)
#pragma unroll
            for (int tt = 0; tt < 4; ++tt) {
                const f16x8 a = *reinterpret_cast<const f16x8*>(
                    sL + (tt * 8 + kc) * 1024 + lane * 16);
                acc[tt] = MFMA(a, Bf[kc], acc[tt]);
            }
        if (l < 3) {
            __syncthreads();    // all waves done reading W_l
            const char* img = ws + ((size_t)(t * 3 + l) << 15);
#pragma unroll
            for (int c = 0; c < 8; ++c)
                gload16(img + (w + c * 4) * 1024 + lane * 16, sL + (w + c * 4) * 1024);
            activate_pack();    // long VALU phase hides the stage latency
            __syncthreads();    // W_{l+1} visible (barrier drains vmcnt)
        }
    }

    // ---- final: out[x] = wl . tanh(acc) + bl (f32 throughout) ----
    float s = 0.0f;
#pragma unroll
    for (int tt = 0; tt < 4; ++tt)
#pragma unroll
        for (int g = 0; g < 4; ++g) {
            const f32x4v wv = *reinterpret_cast<const f32x4v*>(
                sL + LDS_WL + (tt * 32 + g * 8) * 4 + khalf * 16);
#pragma unroll
            for (int q = 0; q < 4; ++q)
                s = fmaf(fast_tanh(acc[tt][4 * g + q]), wv[q], s);
        }
    const float sp = __builtin_bit_cast(float,
        __builtin_amdgcn_ds_bpermute(bpa, __builtin_bit_cast(int, s)));
    const float res = s + sp + *reinterpret_cast<const float*>(sL + LDS_WL + 512);
    if (!khalf) out[(size_t)t * 4096 + xt * 128 + w * 32 + r31] = res;
}

// ---------------------------------------------------------------------------
// Fallback (round-1 kernel, self-contained, known-good) if ws is too small.
// ---------------------------------------------------------------------------
__global__ __launch_bounds__(THREADS, 1)
void mlp_kernel_fb(const float* __restrict__ xin,
                   const float* __restrict__ theta,
                   float* __restrict__ out)
{
    __shared__ __align__(16) _Float16 sH   [128 * LWD];
    __shared__ __align__(16) _Float16 sWhi [LWD * LWD];
    __shared__ __align__(16) _Float16 sWlo [LWD * LWD];
    __shared__ __align__(16) _Float16 sX0hi[128 * IND];
    __shared__ __align__(16) _Float16 sX0lo[128 * IND];
    __shared__ __align__(16) _Float16 sW0hi[LWD * IND];
    __shared__ __align__(16) _Float16 sW0lo[LWD * IND];
    __shared__ float sB[2][LWD];
    __shared__ float sWl[LWD + 1];

    const int tid = threadIdx.x;
    const int bid = blockIdx.x;
    const int sw  = (bid & 7) * 512 + (bid >> 3);
    const int t   = sw >> 5;
    const int xt  = sw & 31;
    const float* __restrict__ th = theta + (size_t)t * PARAMS;
    const float* __restrict__ xg = xin   + (size_t)xt * (128 * IND);

#pragma unroll
    for (int j = 0; j < 2; ++j) {
        const int flat = j * 1024 + tid * 4;
        const float4 v = *reinterpret_cast<const float4*>(xg + flat);
        _Float16 h0 = (_Float16)v.x, h1 = (_Float16)v.y, h2 = (_Float16)v.z, h3 = (_Float16)v.w;
        f16x4 ph = {h0, h1, h2, h3};
        f16x4 pl = {(_Float16)(v.x - (float)h0), (_Float16)(v.y - (float)h1),
                    (_Float16)(v.z - (float)h2), (_Float16)(v.w - (float)h3)};
        *reinterpret_cast<f16x4*>(&sX0hi[flat]) = ph;
        *reinterpret_cast<f16x4*>(&sX0lo[flat]) = pl;
    }
#pragma unroll
    for (int j = 0; j < 2; ++j) {
        const int flat = j * 1024 + tid * 4;
        const float a0 = th[flat], a1 = th[flat + 1], a2 = th[flat + 2], a3 = th[flat + 3];
        _Float16 h0 = (_Float16)a0, h1 = (_Float16)a1, h2 = (_Float16)a2, h3 = (_Float16)a3;
        f16x4 ph = {h0, h1, h2, h3};
        f16x4 pl = {(_Float16)(a0 - (float)h0), (_Float16)(a1 - (float)h1),
                    (_Float16)(a2 - (float)h2), (_Float16)(a3 - (float)h3)};
        *reinterpret_cast<f16x4*>(&sW0hi[flat]) = ph;
        *reinterpret_cast<f16x4*>(&sW0lo[flat]) = pl;
    }
    if (tid < LWD) sB[0][tid] = th[IND * LWD + tid];
    __syncthreads();

    const int lane  = tid & 63;
    const int w     = tid >> 6;
    const int r31   = lane & 31;
    const int khalf = lane >> 5;
    const int hb    = (w >> 1) * 64;
    const int xb    = (w & 1) * 64;
    const int hA0 = hb + r31,  hA1 = hb + 32 + r31;
    const int xB0 = xb + r31,  xB1 = xb + 32 + r31;
    const int swzA0 = (hA0 & 15) << 4, swzA1 = (hA1 & 15) << 4;
    const int swzB0 = (xB0 & 15) << 4, swzB1 = (xB1 & 15) << 4;

    f32x16 acc[2][2];

    {
        const int kb = khalf * 16;
        f16x8 ah[2], al[2], bh[2], bl[2];
        ah[0] = *reinterpret_cast<const f16x8*>((const char*)sW0hi + hA0 * 32 + kb);
        ah[1] = *reinterpret_cast<const f16x8*>((const char*)sW0hi + hA1 * 32 + kb);
        al[0] = *reinterpret_cast<const f16x8*>((const char*)sW0lo + hA0 * 32 + kb);
        al[1] = *reinterpret_cast<const f16x8*>((const char*)sW0lo + hA1 * 32 + kb);
        bh[0] = *reinterpret_cast<const f16x8*>((const char*)sX0hi + xB0 * 32 + kb);
        bh[1] = *reinterpret_cast<const f16x8*>((const char*)sX0hi + xB1 * 32 + kb);
        bl[0] = *reinterpret_cast<const f16x8*>((const char*)sX0lo + xB0 * 32 + kb);
        bl[1] = *reinterpret_cast<const f16x8*>((const char*)sX0lo + xB1 * 32 + kb);
#pragma unroll
        for (int tt = 0; tt < 2; ++tt)
#pragma unroll
            for (int tx = 0; tx < 2; ++tx) {
                f32x16 a;
#pragma unroll
                for (int i = 0; i < 16; ++i) a[i] = 0.0f;
                a = MFMA(al[tt], bh[tx], a);
                a = MFMA(ah[tt], bl[tx], a);
                a = MFMA(ah[tt], bh[tx], a);
                acc[tt][tx] = a;
            }
    }

    auto epilogue = [&](const float* __restrict__ bb) {
#pragma unroll
        for (int tt = 0; tt < 2; ++tt)
#pragma unroll
            for (int tx = 0; tx < 2; ++tx) {
                const int xw  = xb + tx * 32 + r31;
                const int swz = (xw & 15) << 4;
#pragma unroll
                for (int g = 0; g < 4; ++g) {
                    const int hbase = hb + tt * 32 + g * 8 + khalf * 4;
                    f16x4 pk;
#pragma unroll
                    for (int q = 0; q < 4; ++q) {
                        const float v = acc[tt][tx][g * 4 + q] + bb[hbase + q];
                        pk[q] = (_Float16)(1.0f - 2.0f * __builtin_amdgcn_rcpf(
                            __builtin_amdgcn_exp2f(v * 2.8853900817779268f) + 1.0f));
                    }
                    *reinterpret_cast<f16x4*>((char*)sH + xw * 256 + ((hbase * 2) ^ swz)) = pk;
                }
            }
    };

    for (int l = 0; l < 3; ++l) {
        __syncthreads();
        const float* __restrict__ wsrc = th + 2176 + l * 16512;
#pragma unroll
        for (int j = 0; j < 16; ++j) {
            const int flat = j * 1024 + tid * 4;
            const int hrow = flat >> 7;
            const int o    = flat & 127;
            const float a0 = wsrc[flat], a1 = wsrc[flat + 1], a2 = wsrc[flat + 2], a3 = wsrc[flat + 3];
            _Float16 h0 = (_Float16)a0, h1 = (_Float16)a1, h2 = (_Float16)a2, h3 = (_Float16)a3;
            f16x4 ph = {h0, h1, h2, h3};
            f16x4 pl = {(_Float16)(a0 - (float)h0), (_Float16)(a1 - (float)h1),
                        (_Float16)(a2 - (float)h2), (_Float16)(a3 - (float)h3)};
            const int boff = hrow * 256 + ((o * 2) ^ ((hrow & 15) << 4));
            *reinterpret_cast<f16x4*>((char*)sWhi + boff) = ph;
            *reinterpret_cast<f16x4*>((char*)sWlo + boff) = pl;
        }
        if (tid < LWD) sB[(l + 1) & 1][tid] = wsrc[LWD * LWD + tid];
        if (l == 2) {
            if (tid < LWD) sWl[tid] = th[51712 + tid];
            if (tid == LWD) sWl[LWD] = th[51840];
        }

        epilogue(sB[l & 1]);
        __syncthreads();

#pragma unroll
        for (int tt = 0; tt < 2; ++tt)
#pragma unroll
            for (int tx = 0; tx < 2; ++tx)
#pragma unroll
                for (int i = 0; i < 16; ++i) acc[tt][tx][i] = 0.0f;
#pragma unroll
        for (int kc = 0; kc < 8; ++kc) {
            const int kb = kc * 32 + khalf * 16;
            f16x8 ah[2], al[2], bv[2];
            ah[0] = *reinterpret_cast<const f16x8*>((const char*)sWhi + hA0 * 256 + (kb ^ swzA0));
            ah[1] = *reinterpret_cast<const f16x8*>((const char*)sWhi + hA1 * 256 + (kb ^ swzA1));
            al[0] = *reinterpret_cast<const f16x8*>((const char*)sWlo + hA0 * 256 + (kb ^ swzA0));
            al[1] = *reinterpret_cast<const f16x8*>((const char*)sWlo + hA1 * 256 + (kb ^ swzA1));
            bv[0] = *reinterpret_cast<const f16x8*>((const char*)sH   + xB0 * 256 + (kb ^ swzB0));
            bv[1] = *reinterpret_cast<const f16x8*>((const char*)sH   + xB1 * 256 + (kb ^ swzB1));
#pragma unroll
            for (int tt = 0; tt < 2; ++tt)
#pragma unroll
                for (int tx = 0; tx < 2; ++tx) {
                    acc[tt][tx] = MFMA(al[tt], bv[tx], acc[tt][tx]);
                    acc[tt][tx] = MFMA(ah[tt], bv[tx], acc[tt][tx]);
                }
        }
    }

    __syncthreads();
    epilogue(sB[1]);
    __syncthreads();

    if (tid < 128) {
        const int r   = tid;
        const int swz = (r & 15) << 4;
        float s = 0.0f;
#pragma unroll
        for (int c = 0; c < 16; ++c) {
            const int hc = (c + r) & 15;
            const f16x8 hv = *reinterpret_cast<const f16x8*>(
                (const char*)sH + r * 256 + ((hc * 16) ^ swz));
#pragma unroll
            for (int q = 0; q < 8; ++q) s += (float)hv[q] * sWl[hc * 8 + q];
        }
        out[(size_t)t * 4096 + (size_t)xt * 128 + r] = s + sWl[LWD];
    }
}

extern "C" void kernel_launch(void* const* d_in, const int* in_sizes, int n_in,
                              void* d_out, int out_size, void* d_ws, size_t ws_size,
                              hipStream_t stream)
{
    const float* x     = (const float*)d_in[0];
    const float* theta = (const float*)d_in[1];
    float* out = (float*)d_out;

    if (ws_size >= (size_t)WS_TOTAL) {
        prep_kernel<<<dim3(3152), dim3(256), 0, stream>>>(theta, x, (char*)d_ws);
        mlp_main<<<dim3(4096), dim3(THREADS), 0, stream>>>(theta, (const char*)d_ws, out);
    } else {
        mlp_kernel_fb<<<dim3(4096), dim3(THREADS), 0, stream>>>(x, theta, out);
    }
}

// Round 4
// 105.201 us; speedup vs baseline: 2.7949x; 1.0009x over previous
//
#include <hip/hip_runtime.h>

// Batched MLP, round 4: permlane32_swap handoff + register diet + 4 blocks/CU.
// One wave owns 128h x 32x. Activations never touch LDS: MFMA D-frag (col=x,
// row=h) -> tanh -> f16 pack -> v_permlane32_swap_b32 assembles next-layer
// B-frags fully in-register (2 inst/frag, was 8 w/ bpermute+cndmask).
// tt-outer fusion keeps pack-phase transients to 8 regs so the whole kernel
// fits 128 VGPR/wave -> 4 blocks/CU (16 waves/CU).

#define IND      16
#define LWD      128
#define THREADS  256
#define PARAMS   51841

#define WS_L0    12582912                  // 128*3*32768 hidden-W frag images
#define WS_X     (WS_L0 + 128 * 8192)      // + per-t layer0 W images (hi|lo)
#define WS_TOTAL (WS_X + 32 * 8192)        // + per-xtile x images (hi|lo)

#define LDS_B    32768                      // b1..b3: 3*512 B
#define LDS_WL   (32768 + 1536)             // wl (512B) + bl (4B)
#define LDS_SZ   (32768 + 1536 + 520)

typedef _Float16 f16x8 __attribute__((ext_vector_type(8)));
typedef _Float16 f16x4 __attribute__((ext_vector_type(4)));
typedef float    f32x16 __attribute__((ext_vector_type(16)));
typedef float    f32x4v __attribute__((ext_vector_type(4)));
typedef unsigned u32x2  __attribute__((ext_vector_type(2)));

union U4 { unsigned u[4]; f16x8 v; };

// tanh(x) = 1 - 2/(1+2^(2*log2e*x)); saturates correctly at +/-inf, no NaN.
__device__ __forceinline__ float fast_tanh(float v) {
    float e = __builtin_amdgcn_exp2f(v * 2.8853900817779268f);
    return 1.0f - 2.0f * __builtin_amdgcn_rcpf(e + 1.0f);
}
__device__ __forceinline__ unsigned pkf16(float a, float b) {  // RNE pack
    unsigned short ua = __builtin_bit_cast(unsigned short, (_Float16)a);
    unsigned short ub = __builtin_bit_cast(unsigned short, (_Float16)b);
    return (unsigned)ua | ((unsigned)ub << 16);
}
#define MFMA(A, B, C) __builtin_amdgcn_mfma_f32_32x32x16_f16((A), (B), (C), 0, 0, 0)

__device__ __forceinline__ void gload16(const void* g, void* l) {
    __builtin_amdgcn_global_load_lds(
        (const __attribute__((address_space(1))) void*)g,
        (__attribute__((address_space(3))) void*)l, 16, 0, 0);
}

__device__ __forceinline__ void conv8(const float* __restrict__ s, char* hidst, char* lodst) {
    float v[8];
    *reinterpret_cast<float4*>(v)     = *reinterpret_cast<const float4*>(s);
    *reinterpret_cast<float4*>(v + 4) = *reinterpret_cast<const float4*>(s + 4);
    f16x8 hi, lo;
#pragma unroll
    for (int i = 0; i < 8; ++i) {
        hi[i] = (_Float16)v[i];
        lo[i] = (_Float16)(v[i] - (float)hi[i]);
    }
    *reinterpret_cast<f16x8*>(hidst) = hi;
    *reinterpret_cast<f16x8*>(lodst) = lo;
}

// ---------------------------------------------------------------------------
// prep: build images in ws (unchanged from round 3).
// ---------------------------------------------------------------------------
__global__ __launch_bounds__(256)
void prep_kernel(const float* __restrict__ theta, const float* __restrict__ xin,
                 char* __restrict__ ws)
{
    const int b = blockIdx.x, tid = threadIdx.x;
    if (b < 3072) {
        const int t = b / 24, rem = b % 24, li = rem >> 3, hblk = rem & 7;
        const int h  = hblk * 16 + (tid >> 4);
        const int kc = (tid >> 1) & 7, kh = tid & 1;
        const float* src = theta + (size_t)t * PARAMS + 2176 + li * 16512
                         + h * 128 + kc * 16 + kh * 8;
        float v[8];
        *reinterpret_cast<float4*>(v)     = *reinterpret_cast<const float4*>(src);
        *reinterpret_cast<float4*>(v + 4) = *reinterpret_cast<const float4*>(src + 4);
        f16x8 p;
#pragma unroll
        for (int i = 0; i < 8; ++i) p[i] = (_Float16)v[i];
        char* img = ws + ((size_t)(t * 3 + li) << 15);
        *reinterpret_cast<f16x8*>(img + ((h >> 5) * 8 + kc) * 1024
                                      + (kh * 32 + (h & 31)) * 16) = p;
    } else if (b < 3136) {
        const int gid = (b - 3072) * 256 + tid;
        const int t = gid >> 7, h = gid & 127;
        const float* src = theta + (size_t)t * PARAMS + h * IND;
        char* dst = ws + WS_L0 + (size_t)t * 8192 + h * 32;
        conv8(src,     dst,      dst + 4096);
        conv8(src + 8, dst + 16, dst + 4096 + 16);
    } else {
        const int row = (b - 3136) * 256 + tid;
        const float* src = xin + (size_t)row * IND;
        char* dst = ws + WS_X + (size_t)(row >> 7) * 8192 + (row & 127) * 32;
        conv8(src,     dst,      dst + 4096);
        conv8(src + 8, dst + 16, dst + 4096 + 16);
    }
}

// ---------------------------------------------------------------------------
// main
// ---------------------------------------------------------------------------
__global__ __launch_bounds__(THREADS, 4)
void mlp_main(const float* __restrict__ theta, const char* __restrict__ ws,
              float* __restrict__ out)
{
    __shared__ __align__(16) char sL[LDS_SZ];

    const int tid = threadIdx.x, bid = blockIdx.x;
    const int sw  = (bid & 7) * 512 + (bid >> 3);   // XCD-bijective (4096%8==0)
    const int t   = sw >> 5, xt = sw & 31;
    const float* __restrict__ th = theta + (size_t)t * PARAMS;
    const int lane = tid & 63, w = tid >> 6, r31 = lane & 31, khalf = lane >> 5;
    const int bpa  = (lane ^ 32) << 2;

    // ---- stage W1 (async, fragment-linear -> linear LDS) ----
    {
        const char* img = ws + ((size_t)(t * 3) << 15);
#pragma unroll
        for (int c = 0; c < 8; ++c)
            gload16(img + (w + c * 4) * 1024 + lane * 16, sL + (w + c * 4) * 1024);
    }
    // ---- stage biases b1..b3 + wl + bl ----
    for (int k = tid; k < 513; k += THREADS) {
        float v = (k < 384) ? th[2176 + (k >> 7) * 16512 + 16384 + (k & 127)]
                            : th[51712 + (k - 384)];
        *reinterpret_cast<float*>(sL + LDS_B + k * 4) = v;
    }

    // ---- layer 0: acc = b0; acc += W0(hi/lo) * x(hi/lo), K=16 ----
    f32x16 acc[4];
    {
        const char* w0i = ws + WS_L0 + (size_t)t  * 8192;
        const char* xi  = ws + WS_X  + (size_t)xt * 8192;
        const int ro = r31 * 32 + khalf * 16;
        const f16x8 B0h = *reinterpret_cast<const f16x8*>(xi + w * 1024 + ro);
        const f16x8 B0l = *reinterpret_cast<const f16x8*>(xi + 4096 + w * 1024 + ro);
#pragma unroll
        for (int tt = 0; tt < 4; ++tt) {
#pragma unroll
            for (int g = 0; g < 4; ++g) {
                const float4 bv = *reinterpret_cast<const float4*>(
                    th + 2048 + tt * 32 + g * 8 + khalf * 4);
                acc[tt][4 * g + 0] = bv.x; acc[tt][4 * g + 1] = bv.y;
                acc[tt][4 * g + 2] = bv.z; acc[tt][4 * g + 3] = bv.w;
            }
            const f16x8 Ah = *reinterpret_cast<const f16x8*>(w0i + tt * 1024 + ro);
            const f16x8 Al = *reinterpret_cast<const f16x8*>(w0i + 4096 + tt * 1024 + ro);
            acc[tt] = MFMA(Al, B0h, acc[tt]);
            acc[tt] = MFMA(Ah, B0l, acc[tt]);
            acc[tt] = MFMA(Ah, B0h, acc[tt]);
        }
    }

    f16x8 Bf[8];
    // tanh(acc) -> RNE f16 pack -> permlane32_swap assembles next-layer B-frags.
    // Lane holds h = tt*32 + g*8 + khalf*4 + q; run m = tt*4+g. Bf[kc] (k in
    // [16kc,16kc+16)) needs runs 2kc,2kc+1: for khalf=0 lanes u0/u1 are own
    // P*(2kc), u2/u3 are partner(lane+32)'s P*(2kc); for khalf=1 lanes u0/u1
    // are partner(lane-32)'s P*(2kc+1), u2/u3 own P*(2kc+1).
    // v_permlane32_swap_b32(vdst=a, vsrc=b): a' = [a.lo32 | b.lo32 moved to
    // hi lanes], b' = [a.hi32 moved to lo lanes | b.hi32]  ==> with
    // a=P(2kc), b=P(2kc+1): a' is exactly u0-word, b' exactly u2-word.
    auto activate_pack = [&]() {
#pragma unroll
        for (int tt = 0; tt < 4; ++tt) {
            unsigned P0[4], P1[4];
#pragma unroll
            for (int g = 0; g < 4; ++g) {
                const float v0 = fast_tanh(acc[tt][4 * g + 0]);
                const float v1 = fast_tanh(acc[tt][4 * g + 1]);
                const float v2 = fast_tanh(acc[tt][4 * g + 2]);
                const float v3 = fast_tanh(acc[tt][4 * g + 3]);
                P0[g] = pkf16(v0, v1);
                P1[g] = pkf16(v2, v3);
            }
#pragma unroll
            for (int j = 0; j < 2; ++j) {        // kc = 2*tt + j, runs g=2j,2j+1
#if __has_builtin(__builtin_amdgcn_permlane32_swap)
                const u32x2 r0 = __builtin_amdgcn_permlane32_swap(
                    P0[2 * j], P0[2 * j + 1], false, false);
                const u32x2 r1 = __builtin_amdgcn_permlane32_swap(
                    P1[2 * j], P1[2 * j + 1], false, false);
                U4 u;
                u.u[0] = r0[0]; u.u[1] = r1[0]; u.u[2] = r0[1]; u.u[3] = r1[1];
#else
                const unsigned s0 = khalf ? P0[2 * j] : P0[2 * j + 1];
                const unsigned s1 = khalf ? P1[2 * j] : P1[2 * j + 1];
                const unsigned q0 = (unsigned)__builtin_amdgcn_ds_bpermute(bpa, (int)s0);
                const unsigned q1 = (unsigned)__builtin_amdgcn_ds_bpermute(bpa, (int)s1);
                U4 u;
                u.u[0] = khalf ? q0 : P0[2 * j];
                u.u[1] = khalf ? q1 : P1[2 * j];
                u.u[2] = khalf ? P0[2 * j + 1] : q0;
                u.u[3] = khalf ? P1[2 * j + 1] : q1;
#endif
                Bf[2 * tt + j] = u.v;
            }
        }
    };
    activate_pack();
    __syncthreads();            // W1 staged + biases visible

    // ---- hidden layers 1..3 ----
#pragma unroll
    for (int l = 1; l <= 3; ++l) {
        __builtin_amdgcn_s_setprio(1);
#pragma unroll
        for (int tt = 0; tt < 4; ++tt) {
            // acc = bias_l (broadcast ds_read_b128, conflict-free)
#pragma unroll
            for (int g = 0; g < 4; ++g) {
                const f32x4v bv = *reinterpret_cast<const f32x4v*>(
                    sL + LDS_B + (l - 1) * 512 + (tt * 32 + g * 8) * 4 + khalf * 16);
                acc[tt][4 * g + 0] = bv[0]; acc[tt][4 * g + 1] = bv[1];
                acc[tt][4 * g + 2] = bv[2]; acc[tt][4 * g + 3] = bv[3];
            }
            // A-reads: one addr reg (lane*16) + immediate offsets; conflict-free.
#pragma unroll
            for (int kc = 0; kc < 8; ++kc) {
                const f16x8 a = *reinterpret_cast<const f16x8*>(
                    sL + (tt * 8 + kc) * 1024 + lane * 16);
                acc[tt] = MFMA(a, Bf[kc], acc[tt]);
            }
        }
        __builtin_amdgcn_s_setprio(0);
        if (l < 3) {
            __syncthreads();    // all waves done reading W_l
            const char* img = ws + ((size_t)(t * 3 + l) << 15);
#pragma unroll
            for (int c = 0; c < 8; ++c)
                gload16(img + (w + c * 4) * 1024 + lane * 16, sL + (w + c * 4) * 1024);
            activate_pack();    // long VALU phase hides the stage latency
            __syncthreads();    // W_{l+1} visible (barrier drains vmcnt)
        }
    }

    // ---- final: out[x] = wl . tanh(acc) + bl (f32 throughout) ----
    float s = 0.0f;
#pragma unroll
    for (int tt = 0; tt < 4; ++tt)
#pragma unroll
        for (int g = 0; g < 4; ++g) {
            const f32x4v wv = *reinterpret_cast<const f32x4v*>(
                sL + LDS_WL + (tt * 32 + g * 8) * 4 + khalf * 16);
#pragma unroll
            for (int q = 0; q < 4; ++q)
                s = fmaf(fast_tanh(acc[tt][4 * g + q]), wv[q], s);
        }
    const float sp = __builtin_bit_cast(float,
        __builtin_amdgcn_ds_bpermute(bpa, __builtin_bit_cast(int, s)));
    const float res = s + sp + *reinterpret_cast<const float*>(sL + LDS_WL + 512);
    if (!khalf) out[(size_t)t * 4096 + xt * 128 + w * 32 + r31] = res;
}

// ---------------------------------------------------------------------------
// Fallback (round-1 kernel, self-contained, known-good) if ws is too small.
// ---------------------------------------------------------------------------
__global__ __launch_bounds__(THREADS, 1)
void mlp_kernel_fb(const float* __restrict__ xin,
                   const float* __restrict__ theta,
                   float* __restrict__ out)
{
    __shared__ __align__(16) _Float16 sH   [128 * LWD];
    __shared__ __align__(16) _Float16 sWhi [LWD * LWD];
    __shared__ __align__(16) _Float16 sWlo [LWD * LWD];
    __shared__ __align__(16) _Float16 sX0hi[128 * IND];
    __shared__ __align__(16) _Float16 sX0lo[128 * IND];
    __shared__ __align__(16) _Float16 sW0hi[LWD * IND];
    __shared__ __align__(16) _Float16 sW0lo[LWD * IND];
    __shared__ float sB[2][LWD];
    __shared__ float sWl[LWD + 1];

    const int tid = threadIdx.x;
    const int bid = blockIdx.x;
    const int sw  = (bid & 7) * 512 + (bid >> 3);
    const int t   = sw >> 5;
    const int xt  = sw & 31;
    const float* __restrict__ th = theta + (size_t)t * PARAMS;
    const float* __restrict__ xg = xin   + (size_t)xt * (128 * IND);

#pragma unroll
    for (int j = 0; j < 2; ++j) {
        const int flat = j * 1024 + tid * 4;
        const float4 v = *reinterpret_cast<const float4*>(xg + flat);
        _Float16 h0 = (_Float16)v.x, h1 = (_Float16)v.y, h2 = (_Float16)v.z, h3 = (_Float16)v.w;
        f16x4 ph = {h0, h1, h2, h3};
        f16x4 pl = {(_Float16)(v.x - (float)h0), (_Float16)(v.y - (float)h1),
                    (_Float16)(v.z - (float)h2), (_Float16)(v.w - (float)h3)};
        *reinterpret_cast<f16x4*>(&sX0hi[flat]) = ph;
        *reinterpret_cast<f16x4*>(&sX0lo[flat]) = pl;
    }
#pragma unroll
    for (int j = 0; j < 2; ++j) {
        const int flat = j * 1024 + tid * 4;
        const float a0 = th[flat], a1 = th[flat + 1], a2 = th[flat + 2], a3 = th[flat + 3];
        _Float16 h0 = (_Float16)a0, h1 = (_Float16)a1, h2 = (_Float16)a2, h3 = (_Float16)a3;
        f16x4 ph = {h0, h1, h2, h3};
        f16x4 pl = {(_Float16)(a0 - (float)h0), (_Float16)(a1 - (float)h1),
                    (_Float16)(a2 - (float)h2), (_Float16)(a3 - (float)h3)};
        *reinterpret_cast<f16x4*>(&sW0hi[flat]) = ph;
        *reinterpret_cast<f16x4*>(&sW0lo[flat]) = pl;
    }
    if (tid < LWD) sB[0][tid] = th[IND * LWD + tid];
    __syncthreads();

    const int lane  = tid & 63;
    const int w     = tid >> 6;
    const int r31   = lane & 31;
    const int khalf = lane >> 5;
    const int hb    = (w >> 1) * 64;
    const int xb    = (w & 1) * 64;
    const int hA0 = hb + r31,  hA1 = hb + 32 + r31;
    const int xB0 = xb + r31,  xB1 = xb + 32 + r31;
    const int swzA0 = (hA0 & 15) << 4, swzA1 = (hA1 & 15) << 4;
    const int swzB0 = (xB0 & 15) << 4, swzB1 = (xB1 & 15) << 4;

    f32x16 acc[2][2];

    {
        const int kb = khalf * 16;
        f16x8 ah[2], al[2], bh[2], bl[2];
        ah[0] = *reinterpret_cast<const f16x8*>((const char*)sW0hi + hA0 * 32 + kb);
        ah[1] = *reinterpret_cast<const f16x8*>((const char*)sW0hi + hA1 * 32 + kb);
        al[0] = *reinterpret_cast<const f16x8*>((const char*)sW0lo + hA0 * 32 + kb);
        al[1] = *reinterpret_cast<const f16x8*>((const char*)sW0lo + hA1 * 32 + kb);
        bh[0] = *reinterpret_cast<const f16x8*>((const char*)sX0hi + xB0 * 32 + kb);
        bh[1] = *reinterpret_cast<const f16x8*>((const char*)sX0hi + xB1 * 32 + kb);
        bl[0] = *reinterpret_cast<const f16x8*>((const char*)sX0lo + xB0 * 32 + kb);
        bl[1] = *reinterpret_cast<const f16x8*>((const char*)sX0lo + xB1 * 32 + kb);
#pragma unroll
        for (int tt = 0; tt < 2; ++tt)
#pragma unroll
            for (int tx = 0; tx < 2; ++tx) {
                f32x16 a;
#pragma unroll
                for (int i = 0; i < 16; ++i) a[i] = 0.0f;
                a = MFMA(al[tt], bh[tx], a);
                a = MFMA(ah[tt], bl[tx], a);
                a = MFMA(ah[tt], bh[tx], a);
                acc[tt][tx] = a;
            }
    }

    auto epilogue = [&](const float* __restrict__ bb) {
#pragma unroll
        for (int tt = 0; tt < 2; ++tt)
#pragma unroll
            for (int tx = 0; tx < 2; ++tx) {
                const int xw  = xb + tx * 32 + r31;
                const int swz = (xw & 15) << 4;
#pragma unroll
                for (int g = 0; g < 4; ++g) {
                    const int hbase = hb + tt * 32 + g * 8 + khalf * 4;
                    f16x4 pk;
#pragma unroll
                    for (int q = 0; q < 4; ++q) {
                        const float v = acc[tt][tx][g * 4 + q] + bb[hbase + q];
                        pk[q] = (_Float16)(1.0f - 2.0f * __builtin_amdgcn_rcpf(
                            __builtin_amdgcn_exp2f(v * 2.8853900817779268f) + 1.0f));
                    }
                    *reinterpret_cast<f16x4*>((char*)sH + xw * 256 + ((hbase * 2) ^ swz)) = pk;
                }
            }
    };

    for (int l = 0; l < 3; ++l) {
        __syncthreads();
        const float* __restrict__ wsrc = th + 2176 + l * 16512;
#pragma unroll
        for (int j = 0; j < 16; ++j) {
            const int flat = j * 1024 + tid * 4;
            const int hrow = flat >> 7;
            const int o    = flat & 127;
            const float a0 = wsrc[flat], a1 = wsrc[flat + 1], a2 = wsrc[flat + 2], a3 = wsrc[flat + 3];
            _Float16 h0 = (_Float16)a0, h1 = (_Float16)a1, h2 = (_Float16)a2, h3 = (_Float16)a3;
            f16x4 ph = {h0, h1, h2, h3};
            f16x4 pl = {(_Float16)(a0 - (float)h0), (_Float16)(a1 - (float)h1),
                        (_Float16)(a2 - (float)h2), (_Float16)(a3 - (float)h3)};
            const int boff = hrow * 256 + ((o * 2) ^ ((hrow & 15) << 4));
            *reinterpret_cast<f16x4*>((char*)sWhi + boff) = ph;
            *reinterpret_cast<f16x4*>((char*)sWlo + boff) = pl;
        }
        if (tid < LWD) sB[(l + 1) & 1][tid] = wsrc[LWD * LWD + tid];
        if (l == 2) {
            if (tid < LWD) sWl[tid] = th[51712 + tid];
            if (tid == LWD) sWl[LWD] = th[51840];
        }

        epilogue(sB[l & 1]);
        __syncthreads();

#pragma unroll
        for (int tt = 0; tt < 2; ++tt)
#pragma unroll
            for (int tx = 0; tx < 2; ++tx)
#pragma unroll
                for (int i = 0; i < 16; ++i) acc[tt][tx][i] = 0.0f;
#pragma unroll
        for (int kc = 0; kc < 8; ++kc) {
            const int kb = kc * 32 + khalf * 16;
            f16x8 ah[2], al[2], bv[2];
            ah[0] = *reinterpret_cast<const f16x8*>((const char*)sWhi + hA0 * 256 + (kb ^ swzA0));
            ah[1] = *reinterpret_cast<const f16x8*>((const char*)sWhi + hA1 * 256 + (kb ^ swzA1));
            al[0] = *reinterpret_cast<const f16x8*>((const char*)sWlo + hA0 * 256 + (kb ^ swzA0));
            al[1] = *reinterpret_cast<const f16x8*>((const char*)sWlo + hA1 * 256 + (kb ^ swzA1));
            bv[0] = *reinterpret_cast<const f16x8*>((const char*)sH   + xB0 * 256 + (kb ^ swzB0));
            bv[1] = *reinterpret_cast<const f16x8*>((const char*)sH   + xB1 * 256 + (kb ^ swzB1));
#pragma unroll
            for (int tt = 0; tt < 2; ++tt)
#pragma unroll
                for (int tx = 0; tx < 2; ++tx) {
                    acc[tt][tx] = MFMA(al[tt], bv[tx], acc[tt][tx]);
                    acc[tt][tx] = MFMA(ah[tt], bv[tx], acc[tt][tx]);
                }
        }
    }

    __syncthreads();
    epilogue(sB[1]);
    __syncthreads();

    if (tid < 128) {
        const int r   = tid;
        const int swz = (r & 15) << 4;
        float s = 0.0f;
#pragma unroll
        for (int c = 0; c < 16; ++c) {
            const int hc = (c + r) & 15;
            const f16x8 hv = *reinterpret_cast<const f16x8*>(
                (const char*)sH + r * 256 + ((hc * 16) ^ swz));
#pragma unroll
            for (int q = 0; q < 8; ++q) s += (float)hv[q] * sWl[hc * 8 + q];
        }
        out[(size_t)t * 4096 + (size_t)xt * 128 + r] = s + sWl[LWD];
    }
}

extern "C" void kernel_launch(void* const* d_in, const int* in_sizes, int n_in,
                              void* d_out, int out_size, void* d_ws, size_t ws_size,
                              hipStream_t stream)
{
    const float* x     = (const float*)d_in[0];
    const float* theta = (const float*)d_in[1];
    float* out = (float*)d_out;

    if (ws_size >= (size_t)WS_TOTAL) {
        prep_kernel<<<dim3(3152), dim3(256), 0, stream>>>(theta, x, (char*)d_ws);
        mlp_main<<<dim3(4096), dim3(THREADS), 0, stream>>>(theta, (const char*)d_ws, out);
    } else {
        mlp_kernel_fb<<<dim3(4096), dim3(THREADS), 0, stream>>>(x, theta, out);
    }
}